// Round 3
// baseline (263.383 us; speedup 1.0000x reference)
//
#include <hip/hip_runtime.h>
#include <math.h>

// DistanceAggregation v9 — single fused persistent kernel.
// R2 post-mortem: v8's band micro-opts (−16MB fetch, 3-deep prefetch) = exactly
// 0 delta => band neither BW- nor latency-bound. Bottom-up work estimate for
// all 3 kernels ~20us vs ~70us measured kernel region => theory: per-dispatch
// overhead + inter-kernel L2 flush/inv dominates. Fix: fuse band+scan+mean
// into ONE kernel with a manual grid barrier.
//   - NB=512 blocks x 256 thr, __launch_bounds__(256,2) caps VGPR at 256 =>
//     >=2 blocks/CU => all 512 co-resident => barrier is deadlock-free.
//   - monotonic counter barrier (no reset): target NB, then 2*NB. Counter
//     zeroed by an 8B hipMemsetAsync node (ws is poisoned every iteration).
//   - release/acquire via __hip_atomic_* AGENT scope + agent fences (cross-XCD
//     L2 non-coherence: release wbl2 / acquire inv handled by compiler).
//   - phase 1: band (2048 waves >= 2016 runs: single round) + so[]=-1 init.
//   - phase 2: scan chase, 1 wave per batch (blocks 0..B-1, wave 0).
//   - phase 3: mean, 2016 units looped 4/block.
// Phase bodies bit-identical to v8 (absmax preserved). Fallback mono kernel
// retained for tiny ws.

typedef float v4 __attribute__((ext_vector_type(4)));

#define T_F    1000
#define D_DIM  512
#define NV4    128
#define BAND_W 4
#define RUNB   16           // rows per run in band phase
#define RPBB   63           // ceil(999/16)
#define NBF    512          // fused grid size (co-residency-safe)

__device__ __forceinline__ float wave_sum64(float x) {
  x += __shfl_xor(x, 1);
  x += __shfl_xor(x, 2);
  x += __shfl_xor(x, 4);
  x += __shfl_xor(x, 8);
  x += __shfl_xor(x, 16);
  x += __shfl_xor(x, 32);
  return x;
}

__device__ __forceinline__ v4 sel4(bool c, v4 a, v4 b) {
  v4 r;
  r.x = c ? a.x : b.x; r.y = c ? a.y : b.y;
  r.z = c ? a.z : b.z; r.w = c ? a.w : b.w;
  return r;
}

// monotonic grid barrier: every block's thread 0 adds 1 and spins until the
// counter reaches target. ACQ_REL/ACQUIRE at agent scope => wbl2/inv emitted
// by the compiler, covering cross-XCD visibility of prior plain stores.
__device__ __forceinline__ void grid_barrier(int* bar, int target) {
  __syncthreads();                 // drains each wave's stores (vmcnt 0)
  if (threadIdx.x == 0) {
    __hip_atomic_fetch_add(bar, 1, __ATOMIC_ACQ_REL, __HIP_MEMORY_SCOPE_AGENT);
    while (__hip_atomic_load(bar, __ATOMIC_ACQUIRE, __HIP_MEMORY_SCOPE_AGENT) < target)
      __builtin_amdgcn_s_sleep(2);
  }
  __syncthreads();
  __builtin_amdgcn_fence(__ATOMIC_ACQUIRE, "agent");   // all lanes see remote writes
}

// ---------------------------------------------------------------- fused
__global__ __launch_bounds__(256, 2)
void fused_kernel(const float* __restrict__ data, const float* __restrict__ thrp,
                  unsigned long long* __restrict__ d64,   // B*64 packed windows
                  int* __restrict__ scan_out,             // B*1024
                  int* __restrict__ bar,                  // 1 counter (memset 0)
                  float* __restrict__ out, int B) {
  const int lane = threadIdx.x & 63;
  const int wid  = threadIdx.x >> 6;

  // ======== phase 1a: so[] = -1 (parallel across grid; barrier orders vs chase)
  {
    const int total = B * 1024;
    for (int idx = blockIdx.x * 256 + threadIdx.x; idx < total; idx += NBF * 256)
      scan_out[idx] = -1;
  }

  // ======== phase 1b: band (one run per wave; 2048 waves >= B*RPBB=2016)
  const float thr = thrp[0];
  for (int run = blockIdx.x * 4 + wid; run < B * RPBB; run += NBF * 4) {
    const int b   = run / RPBB;
    const int s0i = (run % RPBB) * RUNB;

    const v4* __restrict__ dp = reinterpret_cast<const v4*>(data) + (size_t)b * T_F * NV4;

    const int   wl  = lane & 3;
    float Ff  = 1.9f / (1.0f + expf((float)wl - 1.0f)) + 0.4f;
    float tt  = thr * Ff;
    const float tf2l = tt * tt;

    const int q0 = lane, q1 = 64 + lane;
    v4 ra[8], rb[8];
#pragma unroll
    for (int d = 0; d < 8; ++d) {
      int t = s0i + d; if (t > T_F - 1) t = T_F - 1;
      ra[d] = dp[(size_t)t * NV4 + q0];
      rb[d] = dp[(size_t)t * NV4 + q1];
    }

    v4 pna[3], pnb[3];
    unsigned long long packed = 0ull;

#pragma unroll
    for (int u = 0; u < RUNB; ++u) {
      const int s  = s0i + u;
      const int su = u & 7;
      float p[BAND_W];
#pragma unroll
      for (int w = 0; w < BAND_W; ++w) {
        const int sj = (u + 1 + w) & 7;
        v4 d0 = ra[su] - ra[sj];
        v4 d1 = rb[su] - rb[sj];
        p[w] = d0.x*d0.x + d0.y*d0.y + d0.z*d0.z + d0.w*d0.w
             + d1.x*d1.x + d1.y*d1.y + d1.z*d1.z + d1.w*d1.w;
      }
      if (u >= 3 && (u - 3) < RUNB - 4) {
        const int cs = (u + 5) & 7;
        ra[cs] = pna[u % 3];
        rb[cs] = pnb[u % 3];
      }
      if (u < RUNB - 4) {
        int tn = s + 8; if (tn > T_F - 1) tn = T_F - 1;
        pna[u % 3] = dp[(size_t)tn * NV4 + q0];
        pnb[u % 3] = dp[(size_t)tn * NV4 + q1];
      }

#pragma unroll
      for (int w = 0; w < BAND_W; ++w) {
        p[w] += __shfl_xor(p[w], 1);
        p[w] += __shfl_xor(p[w], 2);
        p[w] += __shfl_xor(p[w], 4);
      }
      const bool bt0 = (lane & 1) != 0, bt1 = (lane & 2) != 0;
      float q0v  = bt0 ? p[1] : p[0];
      float q1v  = bt0 ? p[3] : p[2];
      float comb = bt1 ? q1v : q0v;
      comb += __shfl_xor(comb, 8);
      comb += __shfl_xor(comb, 16);
      comb += __shfl_xor(comb, 32);
      bool valid = (s + 1 + wl) <= (T_F - 1);
      bool bnd   = valid && (comb > tf2l);
      unsigned long long m = __ballot(bnd);
      unsigned long long delta =
          (unsigned long long)__ffsll((unsigned long long)(m & 0xFull));
      packed |= delta << (4 * u);
    }
    if (lane == 0) d64[(size_t)b * 64 + (s0i >> 4)] = packed;
  }

  grid_barrier(bar, NBF);

  // ======== phase 2: scan chase — one wave per batch (blocks 0..B-1, wave 0)
  if (blockIdx.x < B && wid == 0) {
    const int b = blockIdx.x;
    const v4* __restrict__ dp = reinterpret_cast<const v4*>(data) + (size_t)b * T_F * NV4;
    int* __restrict__ so = scan_out + (size_t)b * 1024;

    const unsigned long long v = d64[(size_t)b * 64 + lane];   // lane 63 unused
    unsigned plo = (unsigned)(v & 0xFFFFFFFFull);
    unsigned phi = (unsigned)(v >> 32);

    int s = 0;
    bool need_exact = false;
    while (s < T_F - 1) {
      unsigned lo = (unsigned)__builtin_amdgcn_readlane((int)plo, s >> 4);
      unsigned hi = (unsigned)__builtin_amdgcn_readlane((int)phi, s >> 4);
      unsigned word = (s & 8) ? hi : lo;
      int delta = (word >> ((s & 7) * 4)) & 15;
      if (delta == 0) { need_exact = (s < T_F - 1 - BAND_W); break; }
      s += delta;
      if (lane == 0) so[s] = s - delta;
    }

    if (need_exact) {   // cold: exact continuation from last boundary s
      const int q0 = lane, q1 = 64 + lane;
      int ind = s, f = 0;
      v4 rep0 = dp[(size_t)ind * NV4 + q0];
      v4 rep1 = dp[(size_t)ind * NV4 + q1];
      for (int i = s + 1; i <= T_F - 1; ++i) {
        float av = fminf((float)f - 1.0f, 80.0f);
        float Ff = 1.9f / (1.0f + expf(av)) + 0.4f;
        float t2 = thr * Ff; t2 *= t2;
        v4 x0 = dp[(size_t)i * NV4 + q0];
        v4 x1 = dp[(size_t)i * NV4 + q1];
        v4 d0 = rep0 - x0, d1 = rep1 - x1;
        float part = d0.x*d0.x + d0.y*d0.y + d0.z*d0.z + d0.w*d0.w
                   + d1.x*d1.x + d1.y*d1.y + d1.z*d1.z + d1.w*d1.w;
        float d2 = wave_sum64(part);
        bool bnd = d2 > t2;
        if (bnd) {
          if (lane == 0) so[i] = ind;
          ind = i; f = 0; rep0 = x0; rep1 = x1;
        } else {
          f += 1;
        }
      }
    }
  }

  grid_barrier(bar, 2 * NBF);

  // ======== phase 3: mean — 63*B units, 4 rows per wave per unit
  const int nunits = 63 * B;
  for (int unit = blockIdx.x; unit < nunits; unit += NBF) {
    const int b  = unit / 63;
    const int x  = unit % 63;
    const int i0 = x * 16 + wid * 4;

    const v4* __restrict__ dp  = reinterpret_cast<const v4*>(data) + (size_t)b * T_F * NV4;
    const int* __restrict__ so = scan_out + (size_t)b * 1024;
    v4* __restrict__ mp        = reinterpret_cast<v4*>(out) + (size_t)b * (T_F - 1) * NV4;
    float* __restrict__ fl     = out + (size_t)B * (T_F - 1) * D_DIM + (size_t)b * (T_F - 1);
    const int q0 = lane, q1 = 64 + lane;

    const int4 sv = *reinterpret_cast<const int4*>(so + i0);
    const int sarr[4] = {sv.x, sv.y, sv.z, sv.w};

    const v4 z = {0.f, 0.f, 0.f, 0.f};
#pragma unroll
    for (int q = 0; q < 4; ++q) {
      const int i = i0 + q;
      if (i < 1 || i > T_F - 1) continue;
      const int s = sarr[q];
      if (s < 0) {
        __builtin_nontemporal_store(z, &mp[(size_t)(i - 1) * NV4 + q0]);
        __builtin_nontemporal_store(z, &mp[(size_t)(i - 1) * NV4 + q1]);
        if (lane == 0) __builtin_nontemporal_store(0.0f, &fl[i - 1]);
        continue;
      }
      const int len = i - s;                    // wave-uniform
      v4 a0 = z, a1 = z;
      if (len <= BAND_W) {                      // hot: branch-free masked gather
#pragma unroll
        for (int j = 0; j < BAND_W; ++j) {
          const int t = (j < len) ? (s + j) : (i - 1);
          const float msk = (j < len) ? 1.0f : 0.0f;
          v4 x0 = dp[(size_t)t * NV4 + q0];
          v4 x1 = dp[(size_t)t * NV4 + q1];
          a0.x += x0.x * msk; a0.y += x0.y * msk; a0.z += x0.z * msk; a0.w += x0.w * msk;
          a1.x += x1.x * msk; a1.y += x1.y * msk; a1.z += x1.z * msk; a1.w += x1.w * msk;
        }
      } else {                                  // cold: post-fallback long segment
        for (int t = s; t < i; ++t) {
          a0 += dp[(size_t)t * NV4 + q0];
          a1 += dp[(size_t)t * NV4 + q1];
        }
      }
      const float inv = 1.0f / (float)len;
      a0.x *= inv; a0.y *= inv; a0.z *= inv; a0.w *= inv;
      a1.x *= inv; a1.y *= inv; a1.z *= inv; a1.w *= inv;
      __builtin_nontemporal_store(a0, &mp[(size_t)(i - 1) * NV4 + q0]);
      __builtin_nontemporal_store(a1, &mp[(size_t)(i - 1) * NV4 + q1]);
      if (lane == 0) __builtin_nontemporal_store(1.0f, &fl[i - 1]);
    }
  }
}

// --------------------------------------------------- fallback (R2, green)
__global__ __launch_bounds__(64, 1)
void dist_agg_mono(const float* __restrict__ data,
                   const float* __restrict__ thrp,
                   float* __restrict__ out, int B) {
  const int b    = blockIdx.x;
  const int lane = threadIdx.x;
  const float thr = thrp[0];
  const v4* __restrict__ dp = reinterpret_cast<const v4*>(data) + (size_t)b * T_F * NV4;
  v4* __restrict__ mp       = reinterpret_cast<v4*>(out) + (size_t)b * (T_F - 1) * NV4;
  float* __restrict__ fp    = out + (size_t)B * (T_F - 1) * D_DIM + (size_t)b * (T_F - 1);
  const int s0 = lane, s1 = 64 + lane;

  v4 rep0 = dp[s0], rep1 = dp[s1];
  v4 cs0  = rep0,  cs1  = rep1;
  v4 ss0  = {0.f,0.f,0.f,0.f}, ss1 = {0.f,0.f,0.f,0.f};
  int ind = 0, fi = 0;
  const float F0     = 1.9f / (1.0f + expf(-1.0f)) + 0.4f;
  const float tf0    = thr * F0;
  const float tf2_f0 = tf0 * tf0;
  float tf2 = tf2_f0;

  for (int i = 1; i < T_F; ++i) {
    float an      = fminf((float)fi, 80.0f);
    float Fn      = 1.9f / (1.0f + expf(an)) + 0.4f;
    float tn      = thr * Fn;
    float tf2_inc = tn * tn;
    v4 fa = dp[(size_t)i * NV4 + s0];
    v4 fb = dp[(size_t)i * NV4 + s1];
    v4 d0 = rep0 - fa, d1 = rep1 - fb;
    float part = d0.x*d0.x + d0.y*d0.y + d0.z*d0.z + d0.w*d0.w
               + d1.x*d1.x + d1.y*d1.y + d1.z*d1.z + d1.w*d1.w;
    float dist2 = wave_sum64(part);
    bool bnd = dist2 > tf2;
    float inv = 1.0f / (float)(i - ind);
    v4 df0 = cs0 - ss0, df1 = cs1 - ss1;
    v4 m0, m1, z = {0.f,0.f,0.f,0.f};
    m0.x = df0.x*inv; m0.y = df0.y*inv; m0.z = df0.z*inv; m0.w = df0.w*inv;
    m1.x = df1.x*inv; m1.y = df1.y*inv; m1.z = df1.z*inv; m1.w = df1.w*inv;
    mp[(size_t)(i-1) * NV4 + s0] = sel4(bnd, m0, z);
    mp[(size_t)(i-1) * NV4 + s1] = sel4(bnd, m1, z);
    if (lane == 0) fp[i-1] = bnd ? 1.0f : 0.0f;
    rep0 = sel4(bnd, fa, rep0); rep1 = sel4(bnd, fb, rep1);
    ss0  = sel4(bnd, cs0, ss0); ss1  = sel4(bnd, cs1, ss1);
    ind  = bnd ? i : ind;
    fi   = bnd ? 0 : fi + 1;
    tf2  = bnd ? tf2_f0 : tf2_inc;
    cs0 += fa; cs1 += fb;
  }
}

// ----------------------------------------------------------------- launch
extern "C" void kernel_launch(void* const* d_in, const int* in_sizes, int n_in,
                              void* d_out, int out_size, void* d_ws, size_t ws_size,
                              hipStream_t stream) {
  const float* data = (const float*)d_in[0];
  const float* thr  = (const float*)d_in[1];
  float* out        = (float*)d_out;
  const int B = in_sizes[0] / (T_F * D_DIM);

  // layout: d64 [B*64 u64] | so [B*1024 int] | bar [64B]
  const size_t d64_bytes = (size_t)B * 64 * 8;
  const size_t so_bytes  = (size_t)B * 1024 * 4;
  const size_t need      = d64_bytes + so_bytes + 64;

  if (ws_size >= need && B <= NBF) {
    unsigned long long* d64 = (unsigned long long*)d_ws;
    int* scan_out = (int*)((unsigned char*)d_ws + d64_bytes);
    int* bar      = (int*)((unsigned char*)d_ws + d64_bytes + so_bytes);
    hipMemsetAsync(bar, 0, 64, stream);   // ws is poisoned each iteration
    fused_kernel<<<NBF, 256, 0, stream>>>(data, thr, d64, scan_out, bar, out, B);
  } else {
    dist_agg_mono<<<B, 64, 0, stream>>>(data, thr, out, B);
  }
}

// Round 4
// 217.985 us; speedup vs baseline: 1.2083x; 1.2083x over previous
//
#include <hip/hip_runtime.h>
#include <math.h>

// DistanceAggregation v10 — fused persistent kernel, contention-fixed barrier.
// R3 post-mortem: v9's fused dispatch was 160-178us with VALUBusy 4% and
// nominal FETCH/WRITE => ~90% stalled => grid barrier cost ~50us each. Cause:
// 512 ACQ_REL fetch_adds to the SAME cache line that ~480 blocks spin-load at
// agent scope every ~128cy (hot-line RMW/read storm at the coherent point).
// v10: (a) arrival counter and release flag on separate 128B lines; spinners
// poll only the flag, last arriver writes it (acq-rel chain through the
// counter RMWs makes all blocks' writes visible transitively);
// (b) 256 blocks x 512 thr (same 2048 waves) => 256 arrivals, and NB==#CUs
// => co-residency guaranteed at 1 block/CU (no occupancy gymnastics);
// (c) s_sleep(8) poll cadence. Phase bodies bit-identical to v8/v9.
// Decision rule: fused >120us next bench => fusion structurally loses here,
// revert to v8 split kernels.

typedef float v4 __attribute__((ext_vector_type(4)));

#define T_F    1000
#define D_DIM  512
#define NV4    128
#define BAND_W 4
#define RUNB   16           // rows per run in band phase
#define RPBB   63           // ceil(999/16)
#define NBF    256          // fused grid size == #CUs (co-residency trivial)
#define THRF   512          // threads per fused block (8 waves)

__device__ __forceinline__ float wave_sum64(float x) {
  x += __shfl_xor(x, 1);
  x += __shfl_xor(x, 2);
  x += __shfl_xor(x, 4);
  x += __shfl_xor(x, 8);
  x += __shfl_xor(x, 16);
  x += __shfl_xor(x, 32);
  return x;
}

__device__ __forceinline__ v4 sel4(bool c, v4 a, v4 b) {
  v4 r;
  r.x = c ? a.x : b.x; r.y = c ? a.y : b.y;
  r.z = c ? a.z : b.z; r.w = c ? a.w : b.w;
  return r;
}

// Two-line barrier: cnt (arrivals, RMW) and flag (release generation, read
// by spinners) live on different 128B cache lines. Monotonic generation k.
__device__ __forceinline__ void grid_barrier(int* cnt, int* flag, int k) {
  __syncthreads();                 // vmcnt(0): all block stores drained
  if (threadIdx.x == 0) {
    int old = __hip_atomic_fetch_add(cnt, 1, __ATOMIC_ACQ_REL,
                                     __HIP_MEMORY_SCOPE_AGENT);
    if (old == k * NBF - 1) {
      // last arriver: acq side of RMW saw all earlier releases; publish.
      __hip_atomic_store(flag, k, __ATOMIC_RELEASE, __HIP_MEMORY_SCOPE_AGENT);
    } else {
      while (__hip_atomic_load(flag, __ATOMIC_ACQUIRE,
                               __HIP_MEMORY_SCOPE_AGENT) < k)
        __builtin_amdgcn_s_sleep(8);
    }
  }
  __syncthreads();
  __builtin_amdgcn_fence(__ATOMIC_ACQUIRE, "agent");  // all lanes: inv caches
}

// ---------------------------------------------------------------- fused
__global__ __launch_bounds__(THRF, 2)
void fused_kernel(const float* __restrict__ data, const float* __restrict__ thrp,
                  unsigned long long* __restrict__ d64,   // B*64 packed windows
                  int* __restrict__ scan_out,             // B*1024
                  int* __restrict__ barmem,               // [0]=cnt, [32]=flag
                  float* __restrict__ out, int B) {
  const int lane = threadIdx.x & 63;
  const int wid  = threadIdx.x >> 6;                      // 0..7
  int* cnt  = barmem;
  int* flag = barmem + 32;                                // +128 bytes

  // ======== phase 1a: so[] = -1 (barrier 1 orders vs chase writes)
  {
    const int total = B * 1024;
    for (int idx = blockIdx.x * THRF + threadIdx.x; idx < total; idx += NBF * THRF)
      scan_out[idx] = -1;
  }

  // ======== phase 1b: band (one run per wave; 2048 waves >= B*RPBB=2016)
  const float thr = thrp[0];
  for (int run = blockIdx.x * 8 + wid; run < B * RPBB; run += NBF * 8) {
    const int b   = run / RPBB;
    const int s0i = (run % RPBB) * RUNB;

    const v4* __restrict__ dp = reinterpret_cast<const v4*>(data) + (size_t)b * T_F * NV4;

    const int   wl  = lane & 3;
    float Ff  = 1.9f / (1.0f + expf((float)wl - 1.0f)) + 0.4f;
    float tt  = thr * Ff;
    const float tf2l = tt * tt;

    const int q0 = lane, q1 = 64 + lane;
    v4 ra[8], rb[8];
#pragma unroll
    for (int d = 0; d < 8; ++d) {
      int t = s0i + d; if (t > T_F - 1) t = T_F - 1;
      ra[d] = dp[(size_t)t * NV4 + q0];
      rb[d] = dp[(size_t)t * NV4 + q1];
    }

    v4 pna[3], pnb[3];
    unsigned long long packed = 0ull;

#pragma unroll
    for (int u = 0; u < RUNB; ++u) {
      const int s  = s0i + u;
      const int su = u & 7;
      float p[BAND_W];
#pragma unroll
      for (int w = 0; w < BAND_W; ++w) {
        const int sj = (u + 1 + w) & 7;
        v4 d0 = ra[su] - ra[sj];
        v4 d1 = rb[su] - rb[sj];
        p[w] = d0.x*d0.x + d0.y*d0.y + d0.z*d0.z + d0.w*d0.w
             + d1.x*d1.x + d1.y*d1.y + d1.z*d1.z + d1.w*d1.w;
      }
      if (u >= 3 && (u - 3) < RUNB - 4) {
        const int cs = (u + 5) & 7;
        ra[cs] = pna[u % 3];
        rb[cs] = pnb[u % 3];
      }
      if (u < RUNB - 4) {
        int tn = s + 8; if (tn > T_F - 1) tn = T_F - 1;
        pna[u % 3] = dp[(size_t)tn * NV4 + q0];
        pnb[u % 3] = dp[(size_t)tn * NV4 + q1];
      }

#pragma unroll
      for (int w = 0; w < BAND_W; ++w) {
        p[w] += __shfl_xor(p[w], 1);
        p[w] += __shfl_xor(p[w], 2);
        p[w] += __shfl_xor(p[w], 4);
      }
      const bool bt0 = (lane & 1) != 0, bt1 = (lane & 2) != 0;
      float q0v  = bt0 ? p[1] : p[0];
      float q1v  = bt0 ? p[3] : p[2];
      float comb = bt1 ? q1v : q0v;
      comb += __shfl_xor(comb, 8);
      comb += __shfl_xor(comb, 16);
      comb += __shfl_xor(comb, 32);
      bool valid = (s + 1 + wl) <= (T_F - 1);
      bool bnd   = valid && (comb > tf2l);
      unsigned long long m = __ballot(bnd);
      unsigned long long delta =
          (unsigned long long)__ffsll((unsigned long long)(m & 0xFull));
      packed |= delta << (4 * u);
    }
    if (lane == 0) d64[(size_t)b * 64 + (s0i >> 4)] = packed;
  }

  grid_barrier(cnt, flag, 1);

  // ======== phase 2: scan chase — one wave per batch (blocks 0..B-1, wave 0)
  if (blockIdx.x < B && wid == 0) {
    const int b = blockIdx.x;
    const v4* __restrict__ dp = reinterpret_cast<const v4*>(data) + (size_t)b * T_F * NV4;
    int* __restrict__ so = scan_out + (size_t)b * 1024;

    const unsigned long long v = d64[(size_t)b * 64 + lane];   // lane 63 unused
    unsigned plo = (unsigned)(v & 0xFFFFFFFFull);
    unsigned phi = (unsigned)(v >> 32);

    int s = 0;
    bool need_exact = false;
    while (s < T_F - 1) {
      unsigned lo = (unsigned)__builtin_amdgcn_readlane((int)plo, s >> 4);
      unsigned hi = (unsigned)__builtin_amdgcn_readlane((int)phi, s >> 4);
      unsigned word = (s & 8) ? hi : lo;
      int delta = (word >> ((s & 7) * 4)) & 15;
      if (delta == 0) { need_exact = (s < T_F - 1 - BAND_W); break; }
      s += delta;
      if (lane == 0) so[s] = s - delta;
    }

    if (need_exact) {   // cold: exact continuation from last boundary s
      const int q0 = lane, q1 = 64 + lane;
      int ind = s, f = 0;
      v4 rep0 = dp[(size_t)ind * NV4 + q0];
      v4 rep1 = dp[(size_t)ind * NV4 + q1];
      for (int i = s + 1; i <= T_F - 1; ++i) {
        float av = fminf((float)f - 1.0f, 80.0f);
        float Ff = 1.9f / (1.0f + expf(av)) + 0.4f;
        float t2 = thr * Ff; t2 *= t2;
        v4 x0 = dp[(size_t)i * NV4 + q0];
        v4 x1 = dp[(size_t)i * NV4 + q1];
        v4 d0 = rep0 - x0, d1 = rep1 - x1;
        float part = d0.x*d0.x + d0.y*d0.y + d0.z*d0.z + d0.w*d0.w
                   + d1.x*d1.x + d1.y*d1.y + d1.z*d1.z + d1.w*d1.w;
        float d2 = wave_sum64(part);
        bool bnd = d2 > t2;
        if (bnd) {
          if (lane == 0) so[i] = ind;
          ind = i; f = 0; rep0 = x0; rep1 = x1;
        } else {
          f += 1;
        }
      }
    }
  }

  grid_barrier(cnt, flag, 2);

  // ======== phase 3: mean — 32-row units, 8 waves/block, 4 units/block
  const int nunits = 32 * B;                       // rows x*32..x*32+31
  for (int unit = blockIdx.x; unit < nunits; unit += NBF) {
    const int b  = unit >> 5;
    const int x  = unit & 31;
    const int i0 = x * 32 + wid * 4;               // wid 0..7 -> +0..28

    const v4* __restrict__ dp  = reinterpret_cast<const v4*>(data) + (size_t)b * T_F * NV4;
    const int* __restrict__ so = scan_out + (size_t)b * 1024;
    v4* __restrict__ mp        = reinterpret_cast<v4*>(out) + (size_t)b * (T_F - 1) * NV4;
    float* __restrict__ fl     = out + (size_t)B * (T_F - 1) * D_DIM + (size_t)b * (T_F - 1);
    const int q0 = lane, q1 = 64 + lane;

    // i0 <= 1020: int4 load stays inside the 1024-padded so[] (all inited -1)
    const int4 sv = *reinterpret_cast<const int4*>(so + i0);
    const int sarr[4] = {sv.x, sv.y, sv.z, sv.w};

    const v4 z = {0.f, 0.f, 0.f, 0.f};
#pragma unroll
    for (int q = 0; q < 4; ++q) {
      const int i = i0 + q;
      if (i < 1 || i > T_F - 1) continue;
      const int s = sarr[q];
      if (s < 0) {
        __builtin_nontemporal_store(z, &mp[(size_t)(i - 1) * NV4 + q0]);
        __builtin_nontemporal_store(z, &mp[(size_t)(i - 1) * NV4 + q1]);
        if (lane == 0) __builtin_nontemporal_store(0.0f, &fl[i - 1]);
        continue;
      }
      const int len = i - s;                    // wave-uniform
      v4 a0 = z, a1 = z;
      if (len <= BAND_W) {                      // hot: branch-free masked gather
#pragma unroll
        for (int j = 0; j < BAND_W; ++j) {
          const int t = (j < len) ? (s + j) : (i - 1);
          const float msk = (j < len) ? 1.0f : 0.0f;
          v4 x0 = dp[(size_t)t * NV4 + q0];
          v4 x1 = dp[(size_t)t * NV4 + q1];
          a0.x += x0.x * msk; a0.y += x0.y * msk; a0.z += x0.z * msk; a0.w += x0.w * msk;
          a1.x += x1.x * msk; a1.y += x1.y * msk; a1.z += x1.z * msk; a1.w += x1.w * msk;
        }
      } else {                                  // cold: post-fallback long segment
        for (int t = s; t < i; ++t) {
          a0 += dp[(size_t)t * NV4 + q0];
          a1 += dp[(size_t)t * NV4 + q1];
        }
      }
      const float inv = 1.0f / (float)len;
      a0.x *= inv; a0.y *= inv; a0.z *= inv; a0.w *= inv;
      a1.x *= inv; a1.y *= inv; a1.z *= inv; a1.w *= inv;
      __builtin_nontemporal_store(a0, &mp[(size_t)(i - 1) * NV4 + q0]);
      __builtin_nontemporal_store(a1, &mp[(size_t)(i - 1) * NV4 + q1]);
      if (lane == 0) __builtin_nontemporal_store(1.0f, &fl[i - 1]);
    }
  }
}

// --------------------------------------------------- fallback (R2, green)
__global__ __launch_bounds__(64, 1)
void dist_agg_mono(const float* __restrict__ data,
                   const float* __restrict__ thrp,
                   float* __restrict__ out, int B) {
  const int b    = blockIdx.x;
  const int lane = threadIdx.x;
  const float thr = thrp[0];
  const v4* __restrict__ dp = reinterpret_cast<const v4*>(data) + (size_t)b * T_F * NV4;
  v4* __restrict__ mp       = reinterpret_cast<v4*>(out) + (size_t)b * (T_F - 1) * NV4;
  float* __restrict__ fp    = out + (size_t)B * (T_F - 1) * D_DIM + (size_t)b * (T_F - 1);
  const int s0 = lane, s1 = 64 + lane;

  v4 rep0 = dp[s0], rep1 = dp[s1];
  v4 cs0  = rep0,  cs1  = rep1;
  v4 ss0  = {0.f,0.f,0.f,0.f}, ss1 = {0.f,0.f,0.f,0.f};
  int ind = 0, fi = 0;
  const float F0     = 1.9f / (1.0f + expf(-1.0f)) + 0.4f;
  const float tf0    = thr * F0;
  const float tf2_f0 = tf0 * tf0;
  float tf2 = tf2_f0;

  for (int i = 1; i < T_F; ++i) {
    float an      = fminf((float)fi, 80.0f);
    float Fn      = 1.9f / (1.0f + expf(an)) + 0.4f;
    float tn      = thr * Fn;
    float tf2_inc = tn * tn;
    v4 fa = dp[(size_t)i * NV4 + s0];
    v4 fb = dp[(size_t)i * NV4 + s1];
    v4 d0 = rep0 - fa, d1 = rep1 - fb;
    float part = d0.x*d0.x + d0.y*d0.y + d0.z*d0.z + d0.w*d0.w
               + d1.x*d1.x + d1.y*d1.y + d1.z*d1.z + d1.w*d1.w;
    float dist2 = wave_sum64(part);
    bool bnd = dist2 > tf2;
    float inv = 1.0f / (float)(i - ind);
    v4 df0 = cs0 - ss0, df1 = cs1 - ss1;
    v4 m0, m1, z = {0.f,0.f,0.f,0.f};
    m0.x = df0.x*inv; m0.y = df0.y*inv; m0.z = df0.z*inv; m0.w = df0.w*inv;
    m1.x = df1.x*inv; m1.y = df1.y*inv; m1.z = df1.z*inv; m1.w = df1.w*inv;
    mp[(size_t)(i-1) * NV4 + s0] = sel4(bnd, m0, z);
    mp[(size_t)(i-1) * NV4 + s1] = sel4(bnd, m1, z);
    if (lane == 0) fp[i-1] = bnd ? 1.0f : 0.0f;
    rep0 = sel4(bnd, fa, rep0); rep1 = sel4(bnd, fb, rep1);
    ss0  = sel4(bnd, cs0, ss0); ss1  = sel4(bnd, cs1, ss1);
    ind  = bnd ? i : ind;
    fi   = bnd ? 0 : fi + 1;
    tf2  = bnd ? tf2_f0 : tf2_inc;
    cs0 += fa; cs1 += fb;
  }
}

// ----------------------------------------------------------------- launch
extern "C" void kernel_launch(void* const* d_in, const int* in_sizes, int n_in,
                              void* d_out, int out_size, void* d_ws, size_t ws_size,
                              hipStream_t stream) {
  const float* data = (const float*)d_in[0];
  const float* thr  = (const float*)d_in[1];
  float* out        = (float*)d_out;
  const int B = in_sizes[0] / (T_F * D_DIM);

  // layout: d64 [B*64 u64] | so [B*1024 int] | barmem [256B: cnt@0, flag@128]
  const size_t d64_bytes = (size_t)B * 64 * 8;
  const size_t so_bytes  = (size_t)B * 1024 * 4;
  const size_t need      = d64_bytes + so_bytes + 256;

  if (ws_size >= need && B <= 32) {
    unsigned long long* d64 = (unsigned long long*)d_ws;
    int* scan_out = (int*)((unsigned char*)d_ws + d64_bytes);
    int* barmem   = (int*)((unsigned char*)d_ws + d64_bytes + so_bytes);
    hipMemsetAsync(barmem, 0, 256, stream);   // ws is poisoned each iteration
    fused_kernel<<<NBF, THRF, 0, stream>>>(data, thr, d64, scan_out, barmem, out, B);
  } else {
    dist_agg_mono<<<B, 64, 0, stream>>>(data, thr, out, B);
  }
}

// Round 5
// 214.548 us; speedup vs baseline: 1.2276x; 1.0160x over previous
//
#include <hip/hip_runtime.h>
#include <math.h>

// DistanceAggregation v11 — fused kernel with register-guaranteed band phase.
// R4 post-mortem: barrier fix v10 saved ~35us (160->133) but fused phases run
// ~2x slower than split. VGPR_Count=76 < the 64 VGPRs the band ring alone
// needs => ring demoted to scratch in the big fused function (L2-latency
// reload per row, VALUBusy 5%). v11: band rows are band_row<U> template
// instantiations — every ring/pending index is constexpr => SROA into named
// registers is structurally guaranteed (cannot silently go to scratch).
// Geometry: 256 blocks x 512 thr, launch_bounds(512,2) => 1 block/CU,
// co-residency trivial, VGPR cap 256. Barrier: v10 two-line cnt/flag design.
// Decision rule: VGPR still ~76 or fused >100us => revert to v8 split.

typedef float v4 __attribute__((ext_vector_type(4)));

#define T_F    1000
#define D_DIM  512
#define NV4    128
#define BAND_W 4
#define RUNB   16           // rows per run in band phase
#define RPBB   63           // ceil(999/16)
#define NBF    256          // fused grid size == #CUs (co-residency trivial)
#define THRF   512          // threads per fused block (8 waves)

__device__ __forceinline__ float wave_sum64(float x) {
  x += __shfl_xor(x, 1);
  x += __shfl_xor(x, 2);
  x += __shfl_xor(x, 4);
  x += __shfl_xor(x, 8);
  x += __shfl_xor(x, 16);
  x += __shfl_xor(x, 32);
  return x;
}

__device__ __forceinline__ v4 sel4(bool c, v4 a, v4 b) {
  v4 r;
  r.x = c ? a.x : b.x; r.y = c ? a.y : b.y;
  r.z = c ? a.z : b.z; r.w = c ? a.w : b.w;
  return r;
}

__device__ __forceinline__ float pdist8(v4 a0, v4 b0, v4 a1, v4 b1) {
  v4 d0 = a0 - b0, d1 = a1 - b1;
  return d0.x*d0.x + d0.y*d0.y + d0.z*d0.z + d0.w*d0.w
       + d1.x*d1.x + d1.y*d1.y + d1.z*d1.z + d1.w*d1.w;
}

// Two-line barrier: cnt (arrivals, RMW) and flag (release generation, read
// by spinners) on different 128B cache lines. Monotonic generation k.
__device__ __forceinline__ void grid_barrier(int* cnt, int* flag, int k) {
  __syncthreads();                 // vmcnt(0): all block stores drained
  if (threadIdx.x == 0) {
    int old = __hip_atomic_fetch_add(cnt, 1, __ATOMIC_ACQ_REL,
                                     __HIP_MEMORY_SCOPE_AGENT);
    if (old == k * NBF - 1) {
      __hip_atomic_store(flag, k, __ATOMIC_RELEASE, __HIP_MEMORY_SCOPE_AGENT);
    } else {
      while (__hip_atomic_load(flag, __ATOMIC_ACQUIRE,
                               __HIP_MEMORY_SCOPE_AGENT) < k)
        __builtin_amdgcn_s_sleep(8);
    }
  }
  __syncthreads();
  __builtin_amdgcn_fence(__ATOMIC_ACQUIRE, "agent");  // all lanes: inv caches
}

// One band row, ALL array indices constexpr => registers guaranteed.
template<int U>
__device__ __forceinline__ void band_row(
    v4 (&ra)[8], v4 (&rb)[8], v4 (&pna)[3], v4 (&pnb)[3],
    const v4* __restrict__ dp, int s0i, int q0, int q1,
    int wl, float tf2l, unsigned long long &packed) {
  constexpr int SU  = U & 7;
  constexpr int SJ0 = (U + 1) & 7;
  constexpr int SJ1 = (U + 2) & 7;
  constexpr int SJ2 = (U + 3) & 7;
  constexpr int SJ3 = (U + 4) & 7;
  const int s = s0i + U;

  float p0 = pdist8(ra[SU], ra[SJ0], rb[SU], rb[SJ0]);
  float p1 = pdist8(ra[SU], ra[SJ1], rb[SU], rb[SJ1]);
  float p2 = pdist8(ra[SU], ra[SJ2], rb[SU], rb[SJ2]);
  float p3 = pdist8(ra[SU], ra[SJ3], rb[SU], rb[SJ3]);

  // commit prefetch issued 3 rows ago: frame s+5 lands in slot (U+5)&7
  if constexpr (U >= 3 && (U - 3) < RUNB - 4) {
    constexpr int CS = (U + 5) & 7;
    constexpr int PS = (U - 3) % 3;
    ra[CS] = pna[PS];
    rb[CS] = pnb[PS];
  }
  // issue prefetch of frame s+8 (rows >= RUNB-4 would load dead frames)
  if constexpr (U < RUNB - 4) {
    constexpr int PS = U % 3;
    int tn = s + 8; if (tn > T_F - 1) tn = T_F - 1;
    pna[PS] = dp[(size_t)tn * NV4 + q0];
    pnb[PS] = dp[(size_t)tn * NV4 + q1];
  }

  p0 += __shfl_xor(p0, 1); p0 += __shfl_xor(p0, 2); p0 += __shfl_xor(p0, 4);
  p1 += __shfl_xor(p1, 1); p1 += __shfl_xor(p1, 2); p1 += __shfl_xor(p1, 4);
  p2 += __shfl_xor(p2, 1); p2 += __shfl_xor(p2, 2); p2 += __shfl_xor(p2, 4);
  p3 += __shfl_xor(p3, 1); p3 += __shfl_xor(p3, 2); p3 += __shfl_xor(p3, 4);

  const int lane = q0;                       // q0 == lane
  const bool bt0 = (lane & 1) != 0, bt1 = (lane & 2) != 0;
  float q0v  = bt0 ? p1 : p0;
  float q1v  = bt0 ? p3 : p2;
  float comb = bt1 ? q1v : q0v;
  comb += __shfl_xor(comb, 8);
  comb += __shfl_xor(comb, 16);
  comb += __shfl_xor(comb, 32);
  bool valid = (s + 1 + wl) <= (T_F - 1);
  bool bnd   = valid && (comb > tf2l);
  unsigned long long m = __ballot(bnd);
  unsigned long long delta =
      (unsigned long long)__ffsll((unsigned long long)(m & 0xFull));
  packed |= delta << (4 * U);
}

// ---------------------------------------------------------------- fused
__global__ __launch_bounds__(THRF, 2)
void fused_kernel(const float* __restrict__ data, const float* __restrict__ thrp,
                  unsigned long long* __restrict__ d64,   // B*64 packed windows
                  int* __restrict__ scan_out,             // B*1024
                  int* __restrict__ barmem,               // [0]=cnt, [32]=flag
                  float* __restrict__ out, int B) {
  const int lane = threadIdx.x & 63;
  const int wid  = threadIdx.x >> 6;                      // 0..7
  int* cnt  = barmem;
  int* flag = barmem + 32;                                // +128 bytes

  // ======== phase 1a: so[] = -1 (barrier 1 orders vs chase writes)
  {
    const int total = B * 1024;
    for (int idx = blockIdx.x * THRF + threadIdx.x; idx < total; idx += NBF * THRF)
      scan_out[idx] = -1;
  }

  // ======== phase 1b: band (one run per wave; 2048 waves >= B*RPBB=2016)
  const float thr = thrp[0];
  for (int run = blockIdx.x * 8 + wid; run < B * RPBB; run += NBF * 8) {
    const int b   = run / RPBB;
    const int s0i = (run % RPBB) * RUNB;

    const v4* __restrict__ dp = reinterpret_cast<const v4*>(data) + (size_t)b * T_F * NV4;

    const int   wl  = lane & 3;
    float Ff  = 1.9f / (1.0f + expf((float)wl - 1.0f)) + 0.4f;
    float tt  = thr * Ff;
    const float tf2l = tt * tt;

    const int q0 = lane, q1 = 64 + lane;
    v4 ra[8], rb[8];
#pragma unroll
    for (int d = 0; d < 8; ++d) {
      int t = s0i + d; if (t > T_F - 1) t = T_F - 1;
      ra[d] = dp[(size_t)t * NV4 + q0];
      rb[d] = dp[(size_t)t * NV4 + q1];
    }

    v4 pna[3], pnb[3];
    unsigned long long packed = 0ull;

    band_row< 0>(ra, rb, pna, pnb, dp, s0i, q0, q1, wl, tf2l, packed);
    band_row< 1>(ra, rb, pna, pnb, dp, s0i, q0, q1, wl, tf2l, packed);
    band_row< 2>(ra, rb, pna, pnb, dp, s0i, q0, q1, wl, tf2l, packed);
    band_row< 3>(ra, rb, pna, pnb, dp, s0i, q0, q1, wl, tf2l, packed);
    band_row< 4>(ra, rb, pna, pnb, dp, s0i, q0, q1, wl, tf2l, packed);
    band_row< 5>(ra, rb, pna, pnb, dp, s0i, q0, q1, wl, tf2l, packed);
    band_row< 6>(ra, rb, pna, pnb, dp, s0i, q0, q1, wl, tf2l, packed);
    band_row< 7>(ra, rb, pna, pnb, dp, s0i, q0, q1, wl, tf2l, packed);
    band_row< 8>(ra, rb, pna, pnb, dp, s0i, q0, q1, wl, tf2l, packed);
    band_row< 9>(ra, rb, pna, pnb, dp, s0i, q0, q1, wl, tf2l, packed);
    band_row<10>(ra, rb, pna, pnb, dp, s0i, q0, q1, wl, tf2l, packed);
    band_row<11>(ra, rb, pna, pnb, dp, s0i, q0, q1, wl, tf2l, packed);
    band_row<12>(ra, rb, pna, pnb, dp, s0i, q0, q1, wl, tf2l, packed);
    band_row<13>(ra, rb, pna, pnb, dp, s0i, q0, q1, wl, tf2l, packed);
    band_row<14>(ra, rb, pna, pnb, dp, s0i, q0, q1, wl, tf2l, packed);
    band_row<15>(ra, rb, pna, pnb, dp, s0i, q0, q1, wl, tf2l, packed);

    if (lane == 0) d64[(size_t)b * 64 + (s0i >> 4)] = packed;
  }

  grid_barrier(cnt, flag, 1);

  // ======== phase 2: scan chase — one wave per batch (blocks 0..B-1, wave 0)
  if (blockIdx.x < B && wid == 0) {
    const int b = blockIdx.x;
    const v4* __restrict__ dp = reinterpret_cast<const v4*>(data) + (size_t)b * T_F * NV4;
    int* __restrict__ so = scan_out + (size_t)b * 1024;

    const unsigned long long v = d64[(size_t)b * 64 + lane];   // lane 63 unused
    unsigned plo = (unsigned)(v & 0xFFFFFFFFull);
    unsigned phi = (unsigned)(v >> 32);

    int s = 0;
    bool need_exact = false;
    while (s < T_F - 1) {
      unsigned lo = (unsigned)__builtin_amdgcn_readlane((int)plo, s >> 4);
      unsigned hi = (unsigned)__builtin_amdgcn_readlane((int)phi, s >> 4);
      unsigned word = (s & 8) ? hi : lo;
      int delta = (word >> ((s & 7) * 4)) & 15;
      if (delta == 0) { need_exact = (s < T_F - 1 - BAND_W); break; }
      s += delta;
      if (lane == 0) so[s] = s - delta;
    }

    if (need_exact) {   // cold: exact continuation from last boundary s
      const int q0 = lane, q1 = 64 + lane;
      int ind = s, f = 0;
      v4 rep0 = dp[(size_t)ind * NV4 + q0];
      v4 rep1 = dp[(size_t)ind * NV4 + q1];
      for (int i = s + 1; i <= T_F - 1; ++i) {
        float av = fminf((float)f - 1.0f, 80.0f);
        float Ff = 1.9f / (1.0f + expf(av)) + 0.4f;
        float t2 = thr * Ff; t2 *= t2;
        v4 x0 = dp[(size_t)i * NV4 + q0];
        v4 x1 = dp[(size_t)i * NV4 + q1];
        float part = pdist8(rep0, x0, rep1, x1);
        float d2 = wave_sum64(part);
        bool bnd = d2 > t2;
        if (bnd) {
          if (lane == 0) so[i] = ind;
          ind = i; f = 0; rep0 = x0; rep1 = x1;
        } else {
          f += 1;
        }
      }
    }
  }

  grid_barrier(cnt, flag, 2);

  // ======== phase 3: mean — 32-row units, 8 waves/block, 4 rows/wave
  const int nunits = 32 * B;                       // unit = 32 rows
  for (int unit = blockIdx.x; unit < nunits; unit += NBF) {
    const int b  = unit >> 5;
    const int x  = unit & 31;
    const int i0 = x * 32 + wid * 4;               // wid 0..7 -> +0..28

    const v4* __restrict__ dp  = reinterpret_cast<const v4*>(data) + (size_t)b * T_F * NV4;
    const int* __restrict__ so = scan_out + (size_t)b * 1024;
    v4* __restrict__ mp        = reinterpret_cast<v4*>(out) + (size_t)b * (T_F - 1) * NV4;
    float* __restrict__ fl     = out + (size_t)B * (T_F - 1) * D_DIM + (size_t)b * (T_F - 1);
    const int q0 = lane, q1 = 64 + lane;

    // i0 <= 1020: int4 load stays inside the 1024-padded so[] (all inited -1)
    const int4 sv = *reinterpret_cast<const int4*>(so + i0);
    const int sarr[4] = {sv.x, sv.y, sv.z, sv.w};

    const v4 z = {0.f, 0.f, 0.f, 0.f};
#pragma unroll
    for (int q = 0; q < 4; ++q) {
      const int i = i0 + q;
      if (i < 1 || i > T_F - 1) continue;
      const int s = sarr[q];
      if (s < 0) {
        __builtin_nontemporal_store(z, &mp[(size_t)(i - 1) * NV4 + q0]);
        __builtin_nontemporal_store(z, &mp[(size_t)(i - 1) * NV4 + q1]);
        if (lane == 0) __builtin_nontemporal_store(0.0f, &fl[i - 1]);
        continue;
      }
      const int len = i - s;                    // wave-uniform
      v4 a0 = z, a1 = z;
      if (len <= BAND_W) {                      // hot: branch-free masked gather
#pragma unroll
        for (int j = 0; j < BAND_W; ++j) {
          const int t = (j < len) ? (s + j) : (i - 1);
          const float msk = (j < len) ? 1.0f : 0.0f;
          v4 x0 = dp[(size_t)t * NV4 + q0];
          v4 x1 = dp[(size_t)t * NV4 + q1];
          a0.x += x0.x * msk; a0.y += x0.y * msk; a0.z += x0.z * msk; a0.w += x0.w * msk;
          a1.x += x1.x * msk; a1.y += x1.y * msk; a1.z += x1.z * msk; a1.w += x1.w * msk;
        }
      } else {                                  // cold: post-fallback long segment
        for (int t = s; t < i; ++t) {
          a0 += dp[(size_t)t * NV4 + q0];
          a1 += dp[(size_t)t * NV4 + q1];
        }
      }
      const float inv = 1.0f / (float)len;
      a0.x *= inv; a0.y *= inv; a0.z *= inv; a0.w *= inv;
      a1.x *= inv; a1.y *= inv; a1.z *= inv; a1.w *= inv;
      __builtin_nontemporal_store(a0, &mp[(size_t)(i - 1) * NV4 + q0]);
      __builtin_nontemporal_store(a1, &mp[(size_t)(i - 1) * NV4 + q1]);
      if (lane == 0) __builtin_nontemporal_store(1.0f, &fl[i - 1]);
    }
  }
}

// --------------------------------------------------- fallback (R2, green)
__global__ __launch_bounds__(64, 1)
void dist_agg_mono(const float* __restrict__ data,
                   const float* __restrict__ thrp,
                   float* __restrict__ out, int B) {
  const int b    = blockIdx.x;
  const int lane = threadIdx.x;
  const float thr = thrp[0];
  const v4* __restrict__ dp = reinterpret_cast<const v4*>(data) + (size_t)b * T_F * NV4;
  v4* __restrict__ mp       = reinterpret_cast<v4*>(out) + (size_t)b * (T_F - 1) * NV4;
  float* __restrict__ fp    = out + (size_t)B * (T_F - 1) * D_DIM + (size_t)b * (T_F - 1);
  const int s0 = lane, s1 = 64 + lane;

  v4 rep0 = dp[s0], rep1 = dp[s1];
  v4 cs0  = rep0,  cs1  = rep1;
  v4 ss0  = {0.f,0.f,0.f,0.f}, ss1 = {0.f,0.f,0.f,0.f};
  int ind = 0, fi = 0;
  const float F0     = 1.9f / (1.0f + expf(-1.0f)) + 0.4f;
  const float tf0    = thr * F0;
  const float tf2_f0 = tf0 * tf0;
  float tf2 = tf2_f0;

  for (int i = 1; i < T_F; ++i) {
    float an      = fminf((float)fi, 80.0f);
    float Fn      = 1.9f / (1.0f + expf(an)) + 0.4f;
    float tn      = thr * Fn;
    float tf2_inc = tn * tn;
    v4 fa = dp[(size_t)i * NV4 + s0];
    v4 fb = dp[(size_t)i * NV4 + s1];
    v4 d0 = rep0 - fa, d1 = rep1 - fb;
    float part = d0.x*d0.x + d0.y*d0.y + d0.z*d0.z + d0.w*d0.w
               + d1.x*d1.x + d1.y*d1.y + d1.z*d1.z + d1.w*d1.w;
    float dist2 = wave_sum64(part);
    bool bnd = dist2 > tf2;
    float inv = 1.0f / (float)(i - ind);
    v4 df0 = cs0 - ss0, df1 = cs1 - ss1;
    v4 m0, m1, z = {0.f,0.f,0.f,0.f};
    m0.x = df0.x*inv; m0.y = df0.y*inv; m0.z = df0.z*inv; m0.w = df0.w*inv;
    m1.x = df1.x*inv; m1.y = df1.y*inv; m1.z = df1.z*inv; m1.w = df1.w*inv;
    mp[(size_t)(i-1) * NV4 + s0] = sel4(bnd, m0, z);
    mp[(size_t)(i-1) * NV4 + s1] = sel4(bnd, m1, z);
    if (lane == 0) fp[i-1] = bnd ? 1.0f : 0.0f;
    rep0 = sel4(bnd, fa, rep0); rep1 = sel4(bnd, fb, rep1);
    ss0  = sel4(bnd, cs0, ss0); ss1  = sel4(bnd, cs1, ss1);
    ind  = bnd ? i : ind;
    fi   = bnd ? 0 : fi + 1;
    tf2  = bnd ? tf2_f0 : tf2_inc;
    cs0 += fa; cs1 += fb;
  }
}

// ----------------------------------------------------------------- launch
extern "C" void kernel_launch(void* const* d_in, const int* in_sizes, int n_in,
                              void* d_out, int out_size, void* d_ws, size_t ws_size,
                              hipStream_t stream) {
  const float* data = (const float*)d_in[0];
  const float* thr  = (const float*)d_in[1];
  float* out        = (float*)d_out;
  const int B = in_sizes[0] / (T_F * D_DIM);

  // layout: d64 [B*64 u64] | so [B*1024 int] | barmem [256B: cnt@0, flag@128]
  const size_t d64_bytes = (size_t)B * 64 * 8;
  const size_t so_bytes  = (size_t)B * 1024 * 4;
  const size_t need      = d64_bytes + so_bytes + 256;

  if (ws_size >= need && B <= 32) {
    unsigned long long* d64 = (unsigned long long*)d_ws;
    int* scan_out = (int*)((unsigned char*)d_ws + d64_bytes);
    int* barmem   = (int*)((unsigned char*)d_ws + d64_bytes + so_bytes);
    hipMemsetAsync(barmem, 0, 256, stream);   // ws is poisoned each iteration
    fused_kernel<<<NBF, THRF, 0, stream>>>(data, thr, d64, scan_out, barmem, out, B);
  } else {
    dist_agg_mono<<<B, 64, 0, stream>>>(data, thr, out, B);
  }
}

// Round 8
// 152.499 us; speedup vs baseline: 1.7271x; 1.4069x over previous
//
#include <hip/hip_runtime.h>
#include <math.h>

// DistanceAggregation v12 (second resubmit — R6 and R7 benches were both
// GPUAcquisitionTimeouts; kernel has never run). Revert to v8 split structure
// (measured 152.8us, reproduced twice at +-0.2us) after 3 fused rounds
// regressed (263/218/215us; fused dispatch itself 130-137us with VALUBusy 5%,
// cause never identified — VGPR=76 both with dynamic and constexpr ring
// indices, so scratch-demotion theory falsified). One safe delta vs v8:
// so[]=-1 init moved from scan_kernel into band_kernel (ordered by dispatch
// serialization), removing the init loop + s_waitcnt(0) drain from scan's
// critical-path prologue.
// 1) band_kernel (W=4, ring-8, RUN=16): nibble-packed delta u64 per run +
//    so[]=-1 init. 2) scan_kernel: pure chase (uint2 pre-packed load),
//    exact cold fallback. 3) mean_kernel v3: 4 rows/wave, int4 so-load,
//    branch-free masked-4 hot path, nontemporal stores.
// Fixed harness overhead in dur: ~82us of d_ws/d_out poison fills + d_in
// restore (fills are enqueued before kernel_launch -> no overlap possible).

typedef float v4 __attribute__((ext_vector_type(4)));

#define T_F    1000
#define D_DIM  512
#define NV4    128
#define BAND_W 4
#define RUNB   16           // rows per wave in band kernel
#define RPBB   63           // ceil(999/16)

__device__ __forceinline__ float wave_sum64(float x) {
  x += __shfl_xor(x, 1);
  x += __shfl_xor(x, 2);
  x += __shfl_xor(x, 4);
  x += __shfl_xor(x, 8);
  x += __shfl_xor(x, 16);
  x += __shfl_xor(x, 32);
  return x;
}

__device__ __forceinline__ v4 sel4(bool c, v4 a, v4 b) {
  v4 r;
  r.x = c ? a.x : b.x; r.y = c ? a.y : b.y;
  r.z = c ? a.z : b.z; r.w = c ? a.w : b.w;
  return r;
}

// ---------------------------------------------------------------- kernel 1
__global__ __launch_bounds__(256)
void band_kernel(const float* __restrict__ data, const float* __restrict__ thrp,
                 unsigned char* __restrict__ deltab, int* __restrict__ scan_out,
                 int B) {
  // so[] = -1 init (moved here from scan_kernel; ordered before scan by
  // dispatch serialization). One store for threads with idx in range.
  {
    const int total = B * 1024;
    for (int idx = blockIdx.x * 256 + threadIdx.x; idx < total;
         idx += gridDim.x * 256)
      scan_out[idx] = -1;
  }

  const int lane = threadIdx.x & 63;
  const int wid  = threadIdx.x >> 6;
  const int run  = blockIdx.x * 4 + wid;
  if (run >= B * RPBB) return;
  const int b   = run / RPBB;
  const int s0i = (run % RPBB) * RUNB;       // s0i % 16 == 0

  const v4* __restrict__ dp = reinterpret_cast<const v4*>(data) + (size_t)b * T_F * NV4;
  unsigned char* __restrict__ dbp = deltab + (size_t)b * 1024;

  // per-lane threshold^2 for w = lane&3:  F[w] = 1.9/(1+exp(w-1))+0.4
  const int   wl  = lane & 3;
  const float thr = thrp[0];
  float Ff  = 1.9f / (1.0f + expf((float)wl - 1.0f)) + 0.4f;
  float tt  = thr * Ff;
  const float tf2l = tt * tt;

  const int q0 = lane, q1 = 64 + lane;
  // ring: slot t&7 holds frame t; init frames s0i..s0i+7 (clamped)
  v4 ra[8], rb[8];
#pragma unroll
  for (int d = 0; d < 8; ++d) {
    int t = s0i + d; if (t > T_F - 1) t = T_F - 1;
    ra[d] = dp[(size_t)t * NV4 + q0];
    rb[d] = dp[(size_t)t * NV4 + q1];
  }

  v4 pna[3], pnb[3];                         // 3-deep pending prefetch
  unsigned long long packed = 0ull;          // 16 delta nibbles

#pragma unroll
  for (int u = 0; u < RUNB; ++u) {
    const int s  = s0i + u;                  // segment start; slot = u&7
    const int su = u & 7;
    float p[BAND_W];
#pragma unroll
    for (int w = 0; w < BAND_W; ++w) {
      const int sj = (u + 1 + w) & 7;        // slot of frame s+1+w (compile-time)
      v4 d0 = ra[su] - ra[sj];
      v4 d1 = rb[su] - rb[sj];
      p[w] = d0.x*d0.x + d0.y*d0.y + d0.z*d0.z + d0.w*d0.w
           + d1.x*d1.x + d1.y*d1.y + d1.z*d1.z + d1.w*d1.w;
    }
    // commit pending prefetch issued 3 rows ago: frame s+5 lands in slot
    // (u+5)&7 (held frame s-3, dead after row u-3; first read at row u+1)
    if (u >= 3 && (u - 3) < RUNB - 4) {
      const int cs = (u + 5) & 7;
      ra[cs] = pna[u % 3];
      rb[cs] = pnb[u % 3];
    }
    // issue prefetch of frame s+8 (rows >= RUNB-4 would load frames nobody
    // reads -- skip them: 24 -> 20 frames per run)
    if (u < RUNB - 4) {
      int tn = s + 8; if (tn > T_F - 1) tn = T_F - 1;
      pna[u % 3] = dp[(size_t)tn * NV4 + q0];
      pnb[u % 3] = dp[(size_t)tn * NV4 + q1];
    }

#pragma unroll
    for (int w = 0; w < BAND_W; ++w) {
      p[w] += __shfl_xor(p[w], 1);
      p[w] += __shfl_xor(p[w], 2);
      p[w] += __shfl_xor(p[w], 4);
    }
    const bool bt0 = (lane & 1) != 0, bt1 = (lane & 2) != 0;
    float q0v  = bt0 ? p[1] : p[0];
    float q1v  = bt0 ? p[3] : p[2];
    float comb = bt1 ? q1v : q0v;
    comb += __shfl_xor(comb, 8);
    comb += __shfl_xor(comb, 16);
    comb += __shfl_xor(comb, 32);
    // lane L now holds full dist^2 for w = L&3
    bool valid = (s + 1 + wl) <= (T_F - 1);
    bool bnd   = valid && (comb > tf2l);
    unsigned long long m = __ballot(bnd);
    unsigned long long delta =
        (unsigned long long)__ffsll((unsigned long long)(m & 0xFull)); // 1..4, 0 = none
    packed |= delta << (4 * u);
  }
  // one aligned 8B store of 16 nibbles per run (rows s0i..s0i+15)
  if (lane == 0)
    *reinterpret_cast<unsigned long long*>(dbp + (s0i >> 1)) = packed;
}

// ---------------------------------------------------------------- kernel 2
__global__ __launch_bounds__(64, 1)
void scan_kernel(const float* __restrict__ data, const float* __restrict__ thrp,
                 const unsigned char* __restrict__ deltab,
                 int* __restrict__ scan_out, int B) {
  const int b    = blockIdx.x;
  const int lane = threadIdx.x;
  const v4* __restrict__ dp = reinterpret_cast<const v4*>(data) + (size_t)b * T_F * NV4;
  int* __restrict__ so = scan_out + (size_t)b * 1024;

  // band already nibble-packed: lane L holds rows 16L..16L+15 (lo = rows
  // 0..7 of the window, hi = rows 8..15). so[] pre-inited to -1 by band.
  const uint2 dd = reinterpret_cast<const uint2*>(deltab + (size_t)b * 1024)[lane];
  unsigned plo = dd.x;
  unsigned phi = dd.y;

  int s = 0;
  bool need_exact = false;
  while (s < T_F - 1) {
    unsigned lo = (unsigned)__builtin_amdgcn_readlane((int)plo, s >> 4);
    unsigned hi = (unsigned)__builtin_amdgcn_readlane((int)phi, s >> 4);
    unsigned word = (s & 8) ? hi : lo;
    int delta = (word >> ((s & 7) * 4)) & 15;
    if (delta == 0) { need_exact = (s < T_F - 1 - BAND_W); break; }
    s += delta;
    if (lane == 0) so[s] = s - delta;
  }

  if (need_exact) {   // cold: exact continuation from last boundary s
    const float thr = thrp[0];
    const int q0 = lane, q1 = 64 + lane;
    int ind = s, f = 0;
    v4 rep0 = dp[(size_t)ind * NV4 + q0];
    v4 rep1 = dp[(size_t)ind * NV4 + q1];
    for (int i = s + 1; i <= T_F - 1; ++i) {
      float av = fminf((float)f - 1.0f, 80.0f);
      float Ff = 1.9f / (1.0f + expf(av)) + 0.4f;
      float t2 = thr * Ff; t2 *= t2;
      v4 x0 = dp[(size_t)i * NV4 + q0];
      v4 x1 = dp[(size_t)i * NV4 + q1];
      v4 d0 = rep0 - x0, d1 = rep1 - x1;
      float part = d0.x*d0.x + d0.y*d0.y + d0.z*d0.z + d0.w*d0.w
                 + d1.x*d1.x + d1.y*d1.y + d1.z*d1.z + d1.w*d1.w;
      float d2 = wave_sum64(part);
      bool bnd = d2 > t2;
      if (bnd) {
        if (lane == 0) so[i] = ind;
        ind = i; f = 0; rep0 = x0; rep1 = x1;
      } else {
        f += 1;
      }
    }
  }
}

// ---------------------------------------------------------------- kernel 3
// 4 rows per wave; one int4 so-load gives all gather addresses upfront.
__global__ __launch_bounds__(256)
void mean_kernel(const float* __restrict__ data, const int* __restrict__ scan_out,
                 float* __restrict__ out, int B) {
  const int lane = threadIdx.x & 63;
  const int wv   = threadIdx.x >> 6;
  const int b    = blockIdx.y;
  const int i0   = blockIdx.x * 16 + wv * 4;     // rows i0..i0+3 (row 0 skipped)

  const v4* __restrict__ dp  = reinterpret_cast<const v4*>(data) + (size_t)b * T_F * NV4;
  const int* __restrict__ so = scan_out + (size_t)b * 1024;
  v4* __restrict__ mp        = reinterpret_cast<v4*>(out) + (size_t)b * (T_F - 1) * NV4;
  float* __restrict__ fl     = out + (size_t)B * (T_F - 1) * D_DIM + (size_t)b * (T_F - 1);
  const int q0 = lane, q1 = 64 + lane;

  // all 4 segment starts in one aligned 16B load (so[] is 1024-padded, all
  // entries initialized by band_kernel)
  const int4 sv = *reinterpret_cast<const int4*>(so + i0);
  const int sarr[4] = {sv.x, sv.y, sv.z, sv.w};

  const v4 z = {0.f, 0.f, 0.f, 0.f};
#pragma unroll
  for (int q = 0; q < 4; ++q) {
    const int i = i0 + q;
    if (i < 1 || i > T_F - 1) continue;
    const int s = sarr[q];
    if (s < 0) {
      __builtin_nontemporal_store(z, &mp[(size_t)(i - 1) * NV4 + q0]);
      __builtin_nontemporal_store(z, &mp[(size_t)(i - 1) * NV4 + q1]);
      if (lane == 0) __builtin_nontemporal_store(0.0f, &fl[i - 1]);
      continue;
    }
    const int len = i - s;                    // wave-uniform
    v4 a0 = z, a1 = z;
    if (len <= BAND_W) {                      // hot: branch-free masked gather
#pragma unroll
      for (int j = 0; j < BAND_W; ++j) {
        const int t = (j < len) ? (s + j) : (i - 1);   // clamped, in-segment
        const float msk = (j < len) ? 1.0f : 0.0f;
        v4 x0 = dp[(size_t)t * NV4 + q0];
        v4 x1 = dp[(size_t)t * NV4 + q1];
        a0.x += x0.x * msk; a0.y += x0.y * msk; a0.z += x0.z * msk; a0.w += x0.w * msk;
        a1.x += x1.x * msk; a1.y += x1.y * msk; a1.z += x1.z * msk; a1.w += x1.w * msk;
      }
    } else {                                  // cold: post-fallback long segment
      for (int t = s; t < i; ++t) {
        a0 += dp[(size_t)t * NV4 + q0];
        a1 += dp[(size_t)t * NV4 + q1];
      }
    }
    const float inv = 1.0f / (float)len;
    a0.x *= inv; a0.y *= inv; a0.z *= inv; a0.w *= inv;
    a1.x *= inv; a1.y *= inv; a1.z *= inv; a1.w *= inv;
    __builtin_nontemporal_store(a0, &mp[(size_t)(i - 1) * NV4 + q0]);
    __builtin_nontemporal_store(a1, &mp[(size_t)(i - 1) * NV4 + q1]);
    if (lane == 0) __builtin_nontemporal_store(1.0f, &fl[i - 1]);
  }
}

// --------------------------------------------------- fallback (R2, green)
__global__ __launch_bounds__(64, 1)
void dist_agg_mono(const float* __restrict__ data,
                   const float* __restrict__ thrp,
                   float* __restrict__ out, int B) {
  const int b    = blockIdx.x;
  const int lane = threadIdx.x;
  const float thr = thrp[0];
  const v4* __restrict__ dp = reinterpret_cast<const v4*>(data) + (size_t)b * T_F * NV4;
  v4* __restrict__ mp       = reinterpret_cast<v4*>(out) + (size_t)b * (T_F - 1) * NV4;
  float* __restrict__ fp    = out + (size_t)B * (T_F - 1) * D_DIM + (size_t)b * (T_F - 1);
  const int s0 = lane, s1 = 64 + lane;

  v4 rep0 = dp[s0], rep1 = dp[s1];
  v4 cs0  = rep0,  cs1  = rep1;
  v4 ss0  = {0.f,0.f,0.f,0.f}, ss1 = {0.f,0.f,0.f,0.f};
  int ind = 0, fi = 0;
  const float F0     = 1.9f / (1.0f + expf(-1.0f)) + 0.4f;
  const float tf0    = thr * F0;
  const float tf2_f0 = tf0 * tf0;
  float tf2 = tf2_f0;

  for (int i = 1; i < T_F; ++i) {
    float an      = fminf((float)fi, 80.0f);
    float Fn      = 1.9f / (1.0f + expf(an)) + 0.4f;
    float tn      = thr * Fn;
    float tf2_inc = tn * tn;
    v4 fa = dp[(size_t)i * NV4 + s0];
    v4 fb = dp[(size_t)i * NV4 + s1];
    v4 d0 = rep0 - fa, d1 = rep1 - fb;
    float part = d0.x*d0.x + d0.y*d0.y + d0.z*d0.z + d0.w*d0.w
               + d1.x*d1.x + d1.y*d1.y + d1.z*d1.z + d1.w*d1.w;
    float dist2 = wave_sum64(part);
    bool bnd = dist2 > tf2;
    float inv = 1.0f / (float)(i - ind);
    v4 df0 = cs0 - ss0, df1 = cs1 - ss1;
    v4 m0, m1, z = {0.f,0.f,0.f,0.f};
    m0.x = df0.x*inv; m0.y = df0.y*inv; m0.z = df0.z*inv; m0.w = df0.w*inv;
    m1.x = df1.x*inv; m1.y = df1.y*inv; m1.z = df1.z*inv; m1.w = df1.w*inv;
    mp[(size_t)(i-1) * NV4 + s0] = sel4(bnd, m0, z);
    mp[(size_t)(i-1) * NV4 + s1] = sel4(bnd, m1, z);
    if (lane == 0) fp[i-1] = bnd ? 1.0f : 0.0f;
    rep0 = sel4(bnd, fa, rep0); rep1 = sel4(bnd, fb, rep1);
    ss0  = sel4(bnd, cs0, ss0); ss1  = sel4(bnd, cs1, ss1);
    ind  = bnd ? i : ind;
    fi   = bnd ? 0 : fi + 1;
    tf2  = bnd ? tf2_f0 : tf2_inc;
    cs0 += fa; cs1 += fb;
  }
}

// ----------------------------------------------------------------- launch
extern "C" void kernel_launch(void* const* d_in, const int* in_sizes, int n_in,
                              void* d_out, int out_size, void* d_ws, size_t ws_size,
                              hipStream_t stream) {
  const float* data = (const float*)d_in[0];
  const float* thr  = (const float*)d_in[1];
  float* out        = (float*)d_out;
  const int B = in_sizes[0] / (T_F * D_DIM);

  const size_t need = (size_t)B * 1024 + (size_t)B * 1024 * 4;  // delta + so

  if (ws_size >= need) {
    unsigned char* deltab = (unsigned char*)d_ws;
    int* scan_out = (int*)((unsigned char*)d_ws + (size_t)B * 1024);
    const int runs = B * RPBB;
    band_kernel<<<(runs + 3) / 4, 256, 0, stream>>>(data, thr, deltab, scan_out, B);
    scan_kernel<<<B, 64, 0, stream>>>(data, thr, deltab, scan_out, B);
    mean_kernel<<<dim3(63, B), 256, 0, stream>>>(data, scan_out, out, B);
  } else {
    dist_agg_mono<<<B, 64, 0, stream>>>(data, thr, out, B);
  }
}

// Round 9
// 147.411 us; speedup vs baseline: 1.7867x; 1.0345x over previous
//
#include <hip/hip_runtime.h>
#include <math.h>

// DistanceAggregation v13 — 2-kernel structure: band, then mean+inline-chase.
// R8 accounting (cross-validated vs fused R4/R5: total = dispatch + 81.5us):
// fixed harness overhead ~82us (256MiB ws poison 42us + out poison ~10 + d_in
// restore ~20); split kernel region ~70us = band ~13 + scan ~5-10 + mean
// ~12-20 + 3 launches/gaps. scan's dispatch is the one wholly deletable item:
// band computes delta[s] for EVERY s, so each mean block can redo the chase
// itself (wave 0, ~333 dependent iters ~3us, L2-hot nibbles, early-exit past
// its 16-row window) and publish so via LDS. Deletes: scan dispatch + launch
// + gap, global so[] buffer (init/stores/loads). Exact-fallback preserved
// per-block (walk only to window end). so values identical to v12 by
// construction -> absmax unchanged.
// 1) band_kernel (W=4, ring-8, RUN=16, v8-pure): nibble-packed delta u64/run.
// 2) meanscan_kernel: dim3(63,B)x256; wave0 chase -> LDS so[16]; 4 waves x
//    4 rows, branch-free masked-4 gather, nontemporal stores.

typedef float v4 __attribute__((ext_vector_type(4)));

#define T_F    1000
#define D_DIM  512
#define NV4    128
#define BAND_W 4
#define RUNB   16           // rows per wave in band kernel
#define RPBB   63           // ceil(999/16)

__device__ __forceinline__ float wave_sum64(float x) {
  x += __shfl_xor(x, 1);
  x += __shfl_xor(x, 2);
  x += __shfl_xor(x, 4);
  x += __shfl_xor(x, 8);
  x += __shfl_xor(x, 16);
  x += __shfl_xor(x, 32);
  return x;
}

__device__ __forceinline__ v4 sel4(bool c, v4 a, v4 b) {
  v4 r;
  r.x = c ? a.x : b.x; r.y = c ? a.y : b.y;
  r.z = c ? a.z : b.z; r.w = c ? a.w : b.w;
  return r;
}

// ---------------------------------------------------------------- kernel 1
__global__ __launch_bounds__(256)
void band_kernel(const float* __restrict__ data, const float* __restrict__ thrp,
                 unsigned char* __restrict__ deltab, int B) {
  const int lane = threadIdx.x & 63;
  const int wid  = threadIdx.x >> 6;
  const int run  = blockIdx.x * 4 + wid;
  if (run >= B * RPBB) return;
  const int b   = run / RPBB;
  const int s0i = (run % RPBB) * RUNB;       // s0i % 16 == 0

  const v4* __restrict__ dp = reinterpret_cast<const v4*>(data) + (size_t)b * T_F * NV4;
  unsigned char* __restrict__ dbp = deltab + (size_t)b * 1024;

  // per-lane threshold^2 for w = lane&3:  F[w] = 1.9/(1+exp(w-1))+0.4
  const int   wl  = lane & 3;
  const float thr = thrp[0];
  float Ff  = 1.9f / (1.0f + expf((float)wl - 1.0f)) + 0.4f;
  float tt  = thr * Ff;
  const float tf2l = tt * tt;

  const int q0 = lane, q1 = 64 + lane;
  // ring: slot t&7 holds frame t; init frames s0i..s0i+7 (clamped)
  v4 ra[8], rb[8];
#pragma unroll
  for (int d = 0; d < 8; ++d) {
    int t = s0i + d; if (t > T_F - 1) t = T_F - 1;
    ra[d] = dp[(size_t)t * NV4 + q0];
    rb[d] = dp[(size_t)t * NV4 + q1];
  }

  v4 pna[3], pnb[3];                         // 3-deep pending prefetch
  unsigned long long packed = 0ull;          // 16 delta nibbles

#pragma unroll
  for (int u = 0; u < RUNB; ++u) {
    const int s  = s0i + u;                  // segment start; slot = u&7
    const int su = u & 7;
    float p[BAND_W];
#pragma unroll
    for (int w = 0; w < BAND_W; ++w) {
      const int sj = (u + 1 + w) & 7;        // slot of frame s+1+w (compile-time)
      v4 d0 = ra[su] - ra[sj];
      v4 d1 = rb[su] - rb[sj];
      p[w] = d0.x*d0.x + d0.y*d0.y + d0.z*d0.z + d0.w*d0.w
           + d1.x*d1.x + d1.y*d1.y + d1.z*d1.z + d1.w*d1.w;
    }
    // commit pending prefetch issued 3 rows ago: frame s+5 lands in slot
    // (u+5)&7 (held frame s-3, dead after row u-3; first read at row u+1)
    if (u >= 3 && (u - 3) < RUNB - 4) {
      const int cs = (u + 5) & 7;
      ra[cs] = pna[u % 3];
      rb[cs] = pnb[u % 3];
    }
    // issue prefetch of frame s+8 (rows >= RUNB-4 would load frames nobody
    // reads -- skip them: 24 -> 20 frames per run)
    if (u < RUNB - 4) {
      int tn = s + 8; if (tn > T_F - 1) tn = T_F - 1;
      pna[u % 3] = dp[(size_t)tn * NV4 + q0];
      pnb[u % 3] = dp[(size_t)tn * NV4 + q1];
    }

#pragma unroll
    for (int w = 0; w < BAND_W; ++w) {
      p[w] += __shfl_xor(p[w], 1);
      p[w] += __shfl_xor(p[w], 2);
      p[w] += __shfl_xor(p[w], 4);
    }
    const bool bt0 = (lane & 1) != 0, bt1 = (lane & 2) != 0;
    float q0v  = bt0 ? p[1] : p[0];
    float q1v  = bt0 ? p[3] : p[2];
    float comb = bt1 ? q1v : q0v;
    comb += __shfl_xor(comb, 8);
    comb += __shfl_xor(comb, 16);
    comb += __shfl_xor(comb, 32);
    // lane L now holds full dist^2 for w = L&3
    bool valid = (s + 1 + wl) <= (T_F - 1);
    bool bnd   = valid && (comb > tf2l);
    unsigned long long m = __ballot(bnd);
    unsigned long long delta =
        (unsigned long long)__ffsll((unsigned long long)(m & 0xFull)); // 1..4, 0 = none
    packed |= delta << (4 * u);
  }
  // one aligned 8B store of 16 nibbles per run (rows s0i..s0i+15)
  if (lane == 0)
    *reinterpret_cast<unsigned long long*>(dbp + (s0i >> 1)) = packed;
}

// ---------------------------------------------------------------- kernel 2
// Per block: wave 0 chases delta[] from 0, early-exit past window [X, X+15],
// records so into LDS; then 4 waves x 4 rows compute means (v12 body).
__global__ __launch_bounds__(256)
void meanscan_kernel(const float* __restrict__ data,
                     const float* __restrict__ thrp,
                     const unsigned char* __restrict__ deltab,
                     float* __restrict__ out, int B) {
  const int lane = threadIdx.x & 63;
  const int wv   = threadIdx.x >> 6;
  const int b    = blockIdx.y;
  const int X    = blockIdx.x * 16;              // window rows X..X+15
  const int i0   = X + wv * 4;                   // this wave: rows i0..i0+3

  const v4* __restrict__ dp  = reinterpret_cast<const v4*>(data) + (size_t)b * T_F * NV4;
  v4* __restrict__ mp        = reinterpret_cast<v4*>(out) + (size_t)b * (T_F - 1) * NV4;
  float* __restrict__ fl     = out + (size_t)B * (T_F - 1) * D_DIM + (size_t)b * (T_F - 1);
  const int q0 = lane, q1 = 64 + lane;

  __shared__ int so_l[16];

  if (wv == 0) {
    if (lane < 16) so_l[lane] = -1;
    // lane L holds rows 16L..16L+15 packed nibbles (lo = rows 0..7, hi = 8..15)
    const uint2 dd = reinterpret_cast<const uint2*>(deltab + (size_t)b * 1024)[lane];
    unsigned plo = dd.x;
    unsigned phi = dd.y;

    int s = 0;
    bool need_exact = false;
    const int lim = X + 16;                      // no landings >= lim matter
    while (s < T_F - 1 && s < lim) {
      unsigned lo = (unsigned)__builtin_amdgcn_readlane((int)plo, s >> 4);
      unsigned hi = (unsigned)__builtin_amdgcn_readlane((int)phi, s >> 4);
      unsigned word = (s & 8) ? hi : lo;
      int delta = (word >> ((s & 7) * 4)) & 15;
      if (delta == 0) { need_exact = (s < T_F - 1 - BAND_W); break; }
      int ns = s + delta;
      if (ns >= X && ns < lim && lane == 0) so_l[ns - X] = s;
      s = ns;
    }

    if (need_exact) {   // cold: exact continuation from last boundary s,
      // only as far as this block's window needs (identical so values to v12)
      const float thr = thrp[0];
      int ind = s, f = 0;
      v4 rep0 = dp[(size_t)ind * NV4 + q0];
      v4 rep1 = dp[(size_t)ind * NV4 + q1];
      int iend = X + 15; if (iend > T_F - 1) iend = T_F - 1;
      for (int i = s + 1; i <= iend; ++i) {
        float av = fminf((float)f - 1.0f, 80.0f);
        float Ff = 1.9f / (1.0f + expf(av)) + 0.4f;
        float t2 = thr * Ff; t2 *= t2;
        v4 x0 = dp[(size_t)i * NV4 + q0];
        v4 x1 = dp[(size_t)i * NV4 + q1];
        v4 d0 = rep0 - x0, d1 = rep1 - x1;
        float part = d0.x*d0.x + d0.y*d0.y + d0.z*d0.z + d0.w*d0.w
                   + d1.x*d1.x + d1.y*d1.y + d1.z*d1.z + d1.w*d1.w;
        float d2 = wave_sum64(part);
        bool bnd = d2 > t2;
        if (bnd) {
          if (i >= X && lane == 0) so_l[i - X] = ind;
          ind = i; f = 0; rep0 = x0; rep1 = x1;
        } else {
          f += 1;
        }
      }
    }
  }
  __syncthreads();

  const v4 z = {0.f, 0.f, 0.f, 0.f};
#pragma unroll
  for (int q = 0; q < 4; ++q) {
    const int i = i0 + q;
    if (i < 1 || i > T_F - 1) continue;
    const int s = so_l[wv * 4 + q];
    if (s < 0) {
      __builtin_nontemporal_store(z, &mp[(size_t)(i - 1) * NV4 + q0]);
      __builtin_nontemporal_store(z, &mp[(size_t)(i - 1) * NV4 + q1]);
      if (lane == 0) __builtin_nontemporal_store(0.0f, &fl[i - 1]);
      continue;
    }
    const int len = i - s;                    // wave-uniform
    v4 a0 = z, a1 = z;
    if (len <= BAND_W) {                      // hot: branch-free masked gather
#pragma unroll
      for (int j = 0; j < BAND_W; ++j) {
        const int t = (j < len) ? (s + j) : (i - 1);   // clamped, in-segment
        const float msk = (j < len) ? 1.0f : 0.0f;
        v4 x0 = dp[(size_t)t * NV4 + q0];
        v4 x1 = dp[(size_t)t * NV4 + q1];
        a0.x += x0.x * msk; a0.y += x0.y * msk; a0.z += x0.z * msk; a0.w += x0.w * msk;
        a1.x += x1.x * msk; a1.y += x1.y * msk; a1.z += x1.z * msk; a1.w += x1.w * msk;
      }
    } else {                                  // cold: post-fallback long segment
      for (int t = s; t < i; ++t) {
        a0 += dp[(size_t)t * NV4 + q0];
        a1 += dp[(size_t)t * NV4 + q1];
      }
    }
    const float inv = 1.0f / (float)len;
    a0.x *= inv; a0.y *= inv; a0.z *= inv; a0.w *= inv;
    a1.x *= inv; a1.y *= inv; a1.z *= inv; a1.w *= inv;
    __builtin_nontemporal_store(a0, &mp[(size_t)(i - 1) * NV4 + q0]);
    __builtin_nontemporal_store(a1, &mp[(size_t)(i - 1) * NV4 + q1]);
    if (lane == 0) __builtin_nontemporal_store(1.0f, &fl[i - 1]);
  }
}

// --------------------------------------------------- fallback (R2, green)
__global__ __launch_bounds__(64, 1)
void dist_agg_mono(const float* __restrict__ data,
                   const float* __restrict__ thrp,
                   float* __restrict__ out, int B) {
  const int b    = blockIdx.x;
  const int lane = threadIdx.x;
  const float thr = thrp[0];
  const v4* __restrict__ dp = reinterpret_cast<const v4*>(data) + (size_t)b * T_F * NV4;
  v4* __restrict__ mp       = reinterpret_cast<v4*>(out) + (size_t)b * (T_F - 1) * NV4;
  float* __restrict__ fp    = out + (size_t)B * (T_F - 1) * D_DIM + (size_t)b * (T_F - 1);
  const int s0 = lane, s1 = 64 + lane;

  v4 rep0 = dp[s0], rep1 = dp[s1];
  v4 cs0  = rep0,  cs1  = rep1;
  v4 ss0  = {0.f,0.f,0.f,0.f}, ss1 = {0.f,0.f,0.f,0.f};
  int ind = 0, fi = 0;
  const float F0     = 1.9f / (1.0f + expf(-1.0f)) + 0.4f;
  const float tf0    = thr * F0;
  const float tf2_f0 = tf0 * tf0;
  float tf2 = tf2_f0;

  for (int i = 1; i < T_F; ++i) {
    float an      = fminf((float)fi, 80.0f);
    float Fn      = 1.9f / (1.0f + expf(an)) + 0.4f;
    float tn      = thr * Fn;
    float tf2_inc = tn * tn;
    v4 fa = dp[(size_t)i * NV4 + s0];
    v4 fb = dp[(size_t)i * NV4 + s1];
    v4 d0 = rep0 - fa, d1 = rep1 - fb;
    float part = d0.x*d0.x + d0.y*d0.y + d0.z*d0.z + d0.w*d0.w
               + d1.x*d1.x + d1.y*d1.y + d1.z*d1.z + d1.w*d1.w;
    float dist2 = wave_sum64(part);
    bool bnd = dist2 > tf2;
    float inv = 1.0f / (float)(i - ind);
    v4 df0 = cs0 - ss0, df1 = cs1 - ss1;
    v4 m0, m1, z = {0.f,0.f,0.f,0.f};
    m0.x = df0.x*inv; m0.y = df0.y*inv; m0.z = df0.z*inv; m0.w = df0.w*inv;
    m1.x = df1.x*inv; m1.y = df1.y*inv; m1.z = df1.z*inv; m1.w = df1.w*inv;
    mp[(size_t)(i-1) * NV4 + s0] = sel4(bnd, m0, z);
    mp[(size_t)(i-1) * NV4 + s1] = sel4(bnd, m1, z);
    if (lane == 0) fp[i-1] = bnd ? 1.0f : 0.0f;
    rep0 = sel4(bnd, fa, rep0); rep1 = sel4(bnd, fb, rep1);
    ss0  = sel4(bnd, cs0, ss0); ss1  = sel4(bnd, cs1, ss1);
    ind  = bnd ? i : ind;
    fi   = bnd ? 0 : fi + 1;
    tf2  = bnd ? tf2_f0 : tf2_inc;
    cs0 += fa; cs1 += fb;
  }
}

// ----------------------------------------------------------------- launch
extern "C" void kernel_launch(void* const* d_in, const int* in_sizes, int n_in,
                              void* d_out, int out_size, void* d_ws, size_t ws_size,
                              hipStream_t stream) {
  const float* data = (const float*)d_in[0];
  const float* thr  = (const float*)d_in[1];
  float* out        = (float*)d_out;
  const int B = in_sizes[0] / (T_F * D_DIM);

  const size_t need = (size_t)B * 1024;   // deltab only (so[] is gone)

  if (ws_size >= need) {
    unsigned char* deltab = (unsigned char*)d_ws;
    const int runs = B * RPBB;
    band_kernel<<<(runs + 3) / 4, 256, 0, stream>>>(data, thr, deltab, B);
    meanscan_kernel<<<dim3(63, B), 256, 0, stream>>>(data, thr, deltab, out, B);
  } else {
    dist_agg_mono<<<B, 64, 0, stream>>>(data, thr, out, B);
  }
}